// Round 11
// baseline (759.070 us; speedup 1.0000x reference)
//
#include <hip/hip_runtime.h>
#include <cstdint>
#include <cstddef>

// Problem constants
#define Bb   256
#define Tt   512
#define Ii   300
#define Hh   128
#define G4   512      // 4*H
#define KP   320      // K padded to multiple of 32 for MFMA
#define CH   16       // steps per produced chunk
#define NCH  (Tt/CH)  // 32 chunks

typedef _Float16 h2v   __attribute__((ext_vector_type(2)));
typedef _Float16 half8 __attribute__((ext_vector_type(8)));
typedef float    f32x4 __attribute__((ext_vector_type(4)));

static __device__ __forceinline__ h2v as_h2(unsigned int u){ union{unsigned int u; h2v h;} c; c.u=u; return c.h; }
static __device__ __forceinline__ unsigned int as_u32(h2v h){ union{unsigned int u; h2v h;} c; c.h=h; return c.u; }

#if __has_builtin(__builtin_amdgcn_fdot2)
#define FDOT2(a,b,c) __builtin_amdgcn_fdot2((a),(b),(c),false)
#else
static __device__ __forceinline__ float FDOT2(h2v a, h2v b, float c){
  return c + (float)a[0]*(float)b[0] + (float)a[1]*(float)b[1];
}
#endif

// ---------------- conversion: W_ih -> f16 padded (rows PERMUTED pr=d*4+g), Whh packed, bias sum ---
// Row permutation: output row pr corresponds to original gate row gc = (pr&3)*128 + (pr>>2).
__global__ __launch_bounds__(256) void conv_small(const float* __restrict__ Wih, const float* __restrict__ Whh,
      const float* __restrict__ bih, const float* __restrict__ bhh,
      unsigned int* __restrict__ W16, unsigned int* __restrict__ Whh2, float* __restrict__ bias){
  int idx = blockIdx.x*256 + threadIdx.x;
  if (idx < G4*160){
    int pr = idx/160, kk2 = idx - pr*160, kk = kk2*2;
    int gc = (pr&3)*128 + (pr>>2);
    const float* wr = Wih + (size_t)gc*Ii;
    float v0 = (kk   < Ii) ? wr[kk]   : 0.f;
    float v1 = (kk+1 < Ii) ? wr[kk+1] : 0.f;
    h2v h; h[0]=(_Float16)v0; h[1]=(_Float16)v1;
    W16[idx] = as_u32(h);
  } else if (idx < G4*160 + G4*64){
    int t = idx - G4*160; int pr = t>>6, kk = t&63;
    int gc = (pr&3)*128 + (pr>>2);
    float v0 = Whh[gc*Hh + kk*2], v1 = Whh[gc*Hh + kk*2 + 1];
    h2v h; h[0]=(_Float16)v0; h[1]=(_Float16)v1;
    Whh2[t] = as_u32(h);
  } else if (idx < G4*160 + G4*64 + G4){
    int pr = idx - (G4*160 + G4*64);
    int gc = (pr&3)*128 + (pr>>2);
    bias[pr] = bih[gc] + bhh[gc];
  }
}

// ---------------- fused: per-batch recurrence (waves 0-7, R1 verbatim) + xg producer (waves 8-15) --
// Waves 0-7: R1's measured-optimal recurrence; xc read from LDS ring instead of global xg.
// Waves 8-15: while chunk c is consumed, produce chunk c+1 = x[16 steps x 300] @ W_ih^T + bias
// via MFMA (M=16 = steps), double-buffered ring[2][16][512] in LDS. Producer work per step
// (~4 MFMA + 4 L2 loads) hides in the consumer's measured ~600cyc/step barrier-locked stall;
// all waves hit the same single per-step __syncthreads. Fragment layouts identical to the
// proven gemm16 (A row=l&15,k=(l>>4)*8; B 16B-contiguous from row-major W16; C col=l&15,
// row=(l>>4)*4+reg = step). Eliminates conv_x + gemm16 + all xg HBM traffic (268MB w + r).
__global__ __launch_bounds__(1024,1) void lstm_fused(const float* __restrict__ x,
     const _Float16* __restrict__ Wih16, const float* __restrict__ bias,
     const unsigned int* __restrict__ Whh2,
     const float* __restrict__ fcw, const float* __restrict__ fcb, float* __restrict__ out){
  int tid = threadIdx.x;           // 0..1023
  int b = blockIdx.x;

  __shared__ float ring[2][CH*G4];                      // 64 KB, xg chunks (f32, permuted gates)
  __shared__ __align__(16) _Float16 Axl[CH][KP];        // 10 KB, x chunk as f16 (padded K)
  __shared__ __align__(16) unsigned short hsh[2][128];
  __shared__ float red[128];

  // ---- consumer state (waves 0-7) ----
  int d = tid >> 2, g = tid & 3;
  int b0 = g & 1, b1 = (g >> 1) & 1;
  float km = (g == 2) ? 2.f : 1.f;   // tanh(a) = 2*sigmoid(2a)-1
  h2v w[64];
  float creg = 0.f, hreg = 0.f;

  // ---- producer state (waves 8-15) ----
  int pw  = (tid >> 6) - 8;          // producer wave id 0..7 (valid when tid>=512)
  int pln = tid & 63;
  int pq = pln >> 4, pmr = pln & 15;
  f32x4 acc[4];
  float biasv[4];
  #pragma unroll
  for (int j=0;j<4;j++) acc[j] = (f32x4){0.f,0.f,0.f,0.f};

  // stage x chunk c into Axl as f16 (640 uint4 items; 512 producer threads, 2 items each)
  auto stage_x = [&](int c){
    #pragma unroll
    for (int i=0;i<2;i++){
      int idx = (tid - 512) + i*512;
      if (idx < CH*40){
        int r = idx/40, k = idx - r*40;
        union{ _Float16 h[8]; uint4 u; } o;
        const float* src = x + (size_t)(b*Tt + c*CH + r)*Ii + k*8;
        if (k < 37){
          float4 a4 = *(const float4*)src;
          float4 c4 = *(const float4*)(src+4);
          o.h[0]=(_Float16)a4.x; o.h[1]=(_Float16)a4.y; o.h[2]=(_Float16)a4.z; o.h[3]=(_Float16)a4.w;
          o.h[4]=(_Float16)c4.x; o.h[5]=(_Float16)c4.y; o.h[6]=(_Float16)c4.z; o.h[7]=(_Float16)c4.w;
        } else if (k == 37){
          float4 a4 = *(const float4*)src;
          o.h[0]=(_Float16)a4.x; o.h[1]=(_Float16)a4.y; o.h[2]=(_Float16)a4.z; o.h[3]=(_Float16)a4.w;
          o.h[4]=(_Float16)0.f; o.h[5]=(_Float16)0.f; o.h[6]=(_Float16)0.f; o.h[7]=(_Float16)0.f;
        } else {
          o.u = (uint4){0u,0u,0u,0u};
        }
        *(uint4*)&Axl[r][k*8] = o.u;
      }
    }
  };
  // one K-subtile: 4 B-frag loads (L2) + 1 A ds_read + 4 MFMA
  auto produce_kt = [&](int kt){
    const _Float16* wb = Wih16 + (size_t)(pw*64 + pmr)*KP + kt*32 + pq*8;
    half8 bf0 = *(const half8*)(wb);
    half8 bf1 = *(const half8*)(wb + (size_t)16*KP);
    half8 bf2 = *(const half8*)(wb + (size_t)32*KP);
    half8 bf3 = *(const half8*)(wb + (size_t)48*KP);
    half8 af  = *(const half8*)&Axl[pmr][kt*32 + pq*8];
    acc[0] = __builtin_amdgcn_mfma_f32_16x16x32_f16(af, bf0, acc[0], 0,0,0);
    acc[1] = __builtin_amdgcn_mfma_f32_16x16x32_f16(af, bf1, acc[1], 0,0,0);
    acc[2] = __builtin_amdgcn_mfma_f32_16x16x32_f16(af, bf2, acc[2], 0,0,0);
    acc[3] = __builtin_amdgcn_mfma_f32_16x16x32_f16(af, bf3, acc[3], 0,0,0);
  };
  auto write_ring = [&](int bw){
    #pragma unroll
    for (int j=0;j<4;j++){
      int gate = pw*64 + j*16 + pmr;
      #pragma unroll
      for (int rg=0;rg<4;rg++)
        ring[bw][(pq*4+rg)*G4 + gate] = acc[j][rg] + biasv[j];
      acc[j] = (f32x4){0.f,0.f,0.f,0.f};
    }
  };

  if (tid < 512){
    #pragma unroll
    for (int kk=0; kk<64; ++kk) w[kk] = as_h2(Whh2[tid*64 + kk]);
    if (tid < 128) hsh[0][tid] = 0;
  } else {
    #pragma unroll
    for (int j=0;j<4;j++) biasv[j] = bias[pw*64 + j*16 + pmr];
    stage_x(0);
  }
  __syncthreads();                       // Axl(chunk0) visible to producer waves
  if (tid >= 512){
    #pragma unroll
    for (int kt=0; kt<KP/32; ++kt) produce_kt(kt);
    write_ring(0);                       // chunk 0 -> ring[0]
  }
  __syncthreads();                       // ring[0] visible to consumers

  for (int t=0; t<Tt; ++t){
    if (tid < 512){
      // ---------- consumer: R1 verbatim, xc from ring ----------
      float xc = ring[(t>>4)&1][(t&15)*G4 + tid];
      const uint4* hv = (const uint4*)hsh[t & 1];
      float a0 = xc, a1 = 0.f, a2 = 0.f, a3 = 0.f;
      #pragma unroll
      for (int kq=0; kq<8; ++kq){
        uint4 hq0 = hv[kq*2], hq1 = hv[kq*2+1];
        a0 = FDOT2(as_h2(hq0.x), w[kq*8+0], a0); a1 = FDOT2(as_h2(hq0.y), w[kq*8+1], a1);
        a2 = FDOT2(as_h2(hq0.z), w[kq*8+2], a2); a3 = FDOT2(as_h2(hq0.w), w[kq*8+3], a3);
        a0 = FDOT2(as_h2(hq1.x), w[kq*8+4], a0); a1 = FDOT2(as_h2(hq1.y), w[kq*8+5], a1);
        a2 = FDOT2(as_h2(hq1.z), w[kq*8+6], a2); a3 = FDOT2(as_h2(hq1.w), w[kq*8+7], a3);
      }
      float a = (a0 + a1) + (a2 + a3);
      float s_  = 1.f/(1.f + __expf(-km*a));
      float act = (g == 2) ? (2.f*s_ - 1.f) : s_;
      float u1 = __shfl_xor(act, 1);
      float u2 = __shfl_xor(act, 2);
      float u3 = __shfl_xor(act, 3);
      float pl = b0 ? u1  : act;
      float ph = b0 ? u3  : u2;
      float ql = b0 ? act : u1;
      float qh = b0 ? u2  : u3;
      float i_ = b1 ? ph : pl;
      float f_ = b1 ? qh : ql;
      float g_ = b1 ? pl : ph;
      float o_ = b1 ? ql : qh;
      creg = f_*creg + i_*g_;
      float ec = __expf(2.f*creg); float tc = 1.f - 2.f/(ec+1.f);
      hreg = o_*tc;
      if (g == 0){
        union{ _Float16 f; unsigned short s; } cv; cv.f = (_Float16)hreg;
        hsh[(t+1) & 1][d] = cv.s;
      }
    } else if (t < Tt - CH){
      // ---------- producer: build chunk (t>>4)+1 into ring[(c+1)&1] ----------
      int s = t & 15;
      if (s == 0)                stage_x((t>>4) + 1);
      else if (s >= 2 && s < 12) produce_kt(s - 2);
      else if (s == 12)          write_ring(((t>>4) + 1) & 1);
    }
    __syncthreads();
  }

  // fused FC: out[b] = sum_d h_d * fcw[d] + fcb
  if (tid < 512 && g == 0) red[d] = hreg * fcw[d];
  __syncthreads();
  #pragma unroll
  for (int s2=64; s2>=1; s2>>=1){
    if (tid < s2) red[tid] += red[tid+s2];
    __syncthreads();
  }
  if (tid == 0) out[b] = red[0] + fcb[0];
}

extern "C" void kernel_launch(void* const* d_in, const int* in_sizes, int n_in,
                              void* d_out, int out_size, void* d_ws, size_t ws_size,
                              hipStream_t stream){
  const float* x   = (const float*)d_in[0];
  const float* Wih = (const float*)d_in[1];
  const float* Whh = (const float*)d_in[2];
  const float* bih = (const float*)d_in[3];
  const float* bhh = (const float*)d_in[4];
  const float* fcw = (const float*)d_in[5];
  const float* fcb = (const float*)d_in[6];
  float* out = (float*)d_out;
  char* ws = (char*)d_ws;

  // ws layout (bytes) — only the small converted weights are needed now:
  //   W16  : 83,886,080 .. +327,680     (512*320 f16, rows permuted d*4+g)
  //   Whh2 : 84,213,760 .. +131,072     (512*64 half2, rows permuted d*4+g)
  //   bias : 84,344,832 .. +2,048       (512 f32, permuted d*4+g)
  unsigned int* W16   = (unsigned int*)(ws + 83886080);
  unsigned int* Whh2w = (unsigned int*)(ws + 84213760);
  float*        bias  = (float*)      (ws + 84344832);

  hipLaunchKernelGGL(conv_small, dim3(450), dim3(256), 0, stream, Wih, Whh, bih, bhh, W16, Whh2w, bias);
  hipLaunchKernelGGL(lstm_fused, dim3(256), dim3(1024), 0, stream,
                     x, (const _Float16*)W16, bias, Whh2w, fcw, fcb, out);
}